// Round 4
// baseline (197.620 us; speedup 1.0000x reference)
//
#include <hip/hip_runtime.h>

// BlocksparseFixedSelfAttention: B=4, T=2048, EMB=512, KBLK=64.
// R4: algebraic fusion. Wc1=Wu1*Wv, Wc2=Wu2*Wv (fp32 prep) ->
// one GEMM x@[Wk|Wq|Wc1|Wc2]^T = [K|Q|VU1|VU2] (bf16, ld 2048) ->
// heads: out = S1.VU1_blk + S2.VU2sel + bu  (writes final fp32 out).
// ws (MB): KQV bf16 32 @0 | xb 8 @32 | wcat bf16 2048x512 @40 | biascat f32 8KB @44

typedef unsigned short u16;
typedef __attribute__((ext_vector_type(8))) short short8;
typedef __attribute__((ext_vector_type(4))) float f32x4;

constexpr int TDIM  = 2048;
constexpr int EMB_D = 512;
constexpr int BB    = 4;
constexpr int NBLK  = 32;    // T / 64
constexpr int LDK   = 2048;  // KQV row stride (u16)

__device__ __forceinline__ u16 f2b(float f) {
    unsigned u = __float_as_uint(f);
    unsigned r = (u + 0x7FFFu + ((u >> 16) & 1u)) >> 16;
    return (u16)r;
}

// ---------------------------------------------------------------------------
// cast: y=0 x->xb, y=1 Wk->wcat[0:512], y=2 Wq->wcat[512:1024]
// ---------------------------------------------------------------------------
__global__ __launch_bounds__(256) void cast_k(
    const float* __restrict__ x, const float* __restrict__ wk, const float* __restrict__ wq,
    u16* __restrict__ xb, u16* __restrict__ wcat)
{
    const int s = blockIdx.y;
    int n; const float* src; u16* dst;
    if (s == 0)      { n = 4194304; src = x;  dst = xb; }
    else if (s == 1) { n = 262144;  src = wk; dst = wcat; }
    else             { n = 262144;  src = wq; dst = wcat + 262144; }
    const int idx = (blockIdx.x * 256 + threadIdx.x) * 4;
    if (idx >= n) return;
    float4 v = *(const float4*)(src + idx);
    ushort4 o = { f2b(v.x), f2b(v.y), f2b(v.z), f2b(v.w) };
    *(ushort4*)(dst + idx) = o;
}

// ---------------------------------------------------------------------------
// wc: Wc_half[n][k] = sum_j Wu[n][half*512+j] * Wv[j][k]  (fp32, bf16 out)
// 64x64 tile NN gemm; out -> wcat rows 1024 + half*512 + n.
// ---------------------------------------------------------------------------
__global__ __launch_bounds__(256) void wc_k(
    const float* __restrict__ Wu, const float* __restrict__ Wv, u16* __restrict__ wcat)
{
    const int half = blockIdx.z;
    const int bn = blockIdx.x * 64, bkc = blockIdx.y * 64;
    __shared__ float As[16][64];   // [j][n]
    __shared__ float Bs[16][64];   // [j][k]
    const int tid = threadIdx.x, tx = tid & 15, ty = tid >> 4;
    const int lm = tid >> 2, lj = (tid & 3) << 2;
    float acc[4][4] = {};
    for (int j0 = 0; j0 < 512; j0 += 16) {
        float4 av = *(const float4*)(Wu + (size_t)(bn + lm) * 1024 + half * 512 + j0 + lj);
        float4 bw = *(const float4*)(Wv + (size_t)(j0 + ty) * 512 + bkc + tx * 4);
        __syncthreads();
        As[lj+0][lm]=av.x; As[lj+1][lm]=av.y; As[lj+2][lm]=av.z; As[lj+3][lm]=av.w;
        *(float4*)(&Bs[ty][tx*4]) = bw;
        __syncthreads();
        #pragma unroll
        for (int kk = 0; kk < 16; ++kk) {
            float ar[4], br[4];
            #pragma unroll
            for (int i=0;i<4;i++) ar[i]=As[kk][(ty<<2)+i];
            float4 bb = *(const float4*)(&Bs[kk][tx<<2]);
            br[0]=bb.x; br[1]=bb.y; br[2]=bb.z; br[3]=bb.w;
            #pragma unroll
            for (int i=0;i<4;i++)
                #pragma unroll
                for (int l=0;l<4;l++)
                    acc[i][l] += ar[i]*br[l];
        }
    }
    #pragma unroll
    for (int i=0;i<4;i++) {
        const int n = bn + (ty<<2) + i;
        #pragma unroll
        for (int l=0;l<4;l++)
            wcat[(size_t)(1024 + half*512 + n) * 512 + bkc + (tx<<2) + l] = f2b(acc[i][l]);
    }
}

// ---------------------------------------------------------------------------
// biascat: [bk | bq | Wu1.bv | Wu2.bv]  (2048 floats)
// ---------------------------------------------------------------------------
__global__ __launch_bounds__(256) void bias_k(
    const float* __restrict__ bk, const float* __restrict__ bq,
    const float* __restrict__ bv, const float* __restrict__ Wu,
    float* __restrict__ biascat)
{
    const int g = blockIdx.x * 256 + threadIdx.x;
    if (g < 512) biascat[g] = bk[g];
    else if (g < 1024) biascat[g] = bq[g - 512];
    else {
        const int n = (g - 1024) & 511;
        const int half = (g - 1024) >> 9;
        float s = 0.f;
        const float* wr = Wu + (size_t)n * 1024 + half * 512;
        for (int j = 0; j < 512; j += 4) {
            float4 a = *(const float4*)(wr + j);
            float4 b = *(const float4*)(bv + j);
            s += a.x*b.x + a.y*b.y + a.z*b.z + a.w*b.w;
        }
        biascat[g] = s;
    }
}

// ---------------------------------------------------------------------------
// KQV GEMM: C[m][n] = sum_k xb[m][k]*wcat[n][k] + biascat[n], bf16 out ld 2048.
// 128x128 tile, BK=32, 256 threads (4 waves), m97 structure.
// ---------------------------------------------------------------------------
__global__ __launch_bounds__(256) void kqv_gemm_k(
    const u16* __restrict__ A, const u16* __restrict__ W,
    const float* __restrict__ bias, u16* __restrict__ C)
{
    __shared__ u16 As[128 * 32];
    __shared__ u16 Bs[128 * 32];
    const int bm = blockIdx.x * 128;
    const int bn = blockIdx.y * 128;
    const int tid  = threadIdx.x;
    const int wid  = tid >> 6;
    const int lane = tid & 63;
    const int l15  = lane & 15;
    const int quad = lane >> 4;
    const int wm = (wid & 1) * 64;
    const int wn = (wid >> 1) * 64;

    f32x4 acc[4][4] = {};

    const int srow  = tid >> 2;
    const int skoff = (tid & 3) * 8;
    const u16* Ag = A + (size_t)(bm + srow) * EMB_D + skoff;
    const u16* Wg = W + (size_t)(bn + srow) * EMB_D + skoff;
    char* AsBase = (char*)As + wid * 1024;
    char* BsBase = (char*)Bs + wid * 1024;

    for (int k0 = 0; k0 < EMB_D; k0 += 32) {
        __syncthreads();
        __builtin_amdgcn_global_load_lds(
            (const __attribute__((address_space(1))) void*)(Ag + k0),
            (__attribute__((address_space(3))) void*)AsBase, 16, 0, 0);
        __builtin_amdgcn_global_load_lds(
            (const __attribute__((address_space(1))) void*)(Ag + (size_t)64 * EMB_D + k0),
            (__attribute__((address_space(3))) void*)(AsBase + 4096), 16, 0, 0);
        __builtin_amdgcn_global_load_lds(
            (const __attribute__((address_space(1))) void*)(Wg + k0),
            (__attribute__((address_space(3))) void*)BsBase, 16, 0, 0);
        __builtin_amdgcn_global_load_lds(
            (const __attribute__((address_space(1))) void*)(Wg + (size_t)64 * EMB_D + k0),
            (__attribute__((address_space(3))) void*)(BsBase + 4096), 16, 0, 0);
        __syncthreads();

        short8 a[4], b[4];
        #pragma unroll
        for (int i = 0; i < 4; ++i)
            a[i] = *(const short8*)((const short*)As + (wm + 16 * i + l15) * 32 + quad * 8);
        #pragma unroll
        for (int j = 0; j < 4; ++j)
            b[j] = *(const short8*)((const short*)Bs + (wn + 16 * j + l15) * 32 + quad * 8);
        #pragma unroll
        for (int i = 0; i < 4; ++i)
            #pragma unroll
            for (int j = 0; j < 4; ++j)
                acc[i][j] = __builtin_amdgcn_mfma_f32_16x16x32_bf16(a[i], b[j], acc[i][j], 0, 0, 0);
    }

    #pragma unroll
    for (int i = 0; i < 4; ++i) {
        #pragma unroll
        for (int j = 0; j < 4; ++j) {
            const int col = bn + wn + 16 * j + l15;
            const float bvv = bias[col];
            #pragma unroll
            for (int r = 0; r < 4; ++r) {
                const int row = bm + wm + 16 * i + quad * 4 + r;
                C[(size_t)row * LDK + col] = f2b(acc[i][j][r] + bvv);
            }
        }
    }
}

// ---------------------------------------------------------------------------
// heads: grid (32 blk, 4 b, 4 e-chunk). Per block:
//  S1 = K_blk.Q_blk^T (64x64, K=512) masked c<=r
//  S2 = K_blk.Qsel^T  (64x32, K=512) masked m<=blk
//  out[:, e0:e0+128] = [S1|S2] @ [VU1_blk ; VU2sel][:, e0:e0+128] + bu
// S via direct-global MFMA frags; VU^T staged in LDS (stride 104 u16: 16B-
// aligned, 2-way banks = free). K=96 PV in one MFMA pass.
// ---------------------------------------------------------------------------
__global__ __launch_bounds__(256) void heads_k(
    const u16* __restrict__ KQV, const float* __restrict__ bu, float* __restrict__ out)
{
    __shared__ u16 sm1[64 * 104];    // [row][0:64 S1 | 64:96 S2]
    __shared__ u16 sm2[128 * 104];   // [e][0:64 VU1^T | 64:96 VU2sel^T]
    const int blk = blockIdx.x, b = blockIdx.y;
    const int e0 = blockIdx.z * 128;
    const int tid = threadIdx.x;
    const int wid = tid >> 6, lane = tid & 63;
    const int l15 = lane & 15, quad = lane >> 4;
    const size_t row0 = (size_t)b * TDIM + (size_t)blk * 64;
    const int srow_base = 16 * wid + quad * 4;

    // ---- Phase A: S1 (64x64) and S2 (64x32), K=512 ----
    f32x4 s1[4] = {}; f32x4 s2[2] = {};
    const u16* Kp  = KQV + (row0 + 16 * wid + l15) * (size_t)LDK + quad * 8;
    const u16* Qp  = KQV + (row0 + l15) * (size_t)LDK + 512 + quad * 8;
    const u16* Qsp = KQV + ((size_t)b * TDIM + (size_t)64 * l15) * (size_t)LDK + 512 + quad * 8;
    for (int ks = 0; ks < 16; ++ks) {
        short8 af = *(const short8*)(Kp + 32 * ks);
        #pragma unroll
        for (int j = 0; j < 4; ++j) {
            short8 bf = *(const short8*)(Qp + (size_t)(16 * j) * LDK + 32 * ks);
            s1[j] = __builtin_amdgcn_mfma_f32_16x16x32_bf16(af, bf, s1[j], 0, 0, 0);
        }
        #pragma unroll
        for (int j = 0; j < 2; ++j) {
            short8 bf = *(const short8*)(Qsp + (size_t)(64 * 16 * j) * LDK + 32 * ks);
            s2[j] = __builtin_amdgcn_mfma_f32_16x16x32_bf16(af, bf, s2[j], 0, 0, 0);
        }
    }
    // mask + store to LDS bf16
    #pragma unroll
    for (int j = 0; j < 4; ++j)
        #pragma unroll
        for (int r = 0; r < 4; ++r) {
            const int rr = srow_base + r;
            const int cc = 16 * j + l15;
            sm1[rr * 104 + cc] = f2b((cc <= rr) ? s1[j][r] : 0.0f);
        }
    #pragma unroll
    for (int j = 0; j < 2; ++j)
        #pragma unroll
        for (int r = 0; r < 4; ++r) {
            const int m  = 16 * j + l15;
            const int rr = srow_base + r;
            sm1[rr * 104 + 64 + m] = f2b((m <= blk) ? s2[j][r] : 0.0f);
        }
    // ---- stage VU1^T [e][c] and VU2sel^T [e][m] ----
    #pragma unroll
    for (int it = 0; it < 4; ++it) {
        const int id = tid + 256 * it;
        const int c  = id & 63;
        const int eo = (id >> 6) * 8;
        short8 v = *(const short8*)(KQV + (row0 + c) * (size_t)LDK + 1024 + e0 + eo);
        #pragma unroll
        for (int i = 0; i < 8; ++i) sm2[(eo + i) * 104 + c] = (u16)v[i];
    }
    #pragma unroll
    for (int it = 0; it < 2; ++it) {
        const int id = tid + 256 * it;
        const int m  = id & 31;
        const int eo = (id >> 5) * 8;
        short8 v = *(const short8*)(KQV + ((size_t)b * TDIM + 64 * m) * (size_t)LDK + 1536 + e0 + eo);
        #pragma unroll
        for (int i = 0; i < 8; ++i) sm2[(eo + i) * 104 + 64 + m] = (u16)v[i];
    }
    __syncthreads();
    // ---- Phase B: out = [S1|S2] @ sm2^T  (K=96, N=128) ----
    f32x4 o[8] = {};
    const u16* arow = sm1 + (16 * wid + l15) * 104;
    #pragma unroll
    for (int ks = 0; ks < 3; ++ks) {
        short8 as = *(const short8*)(arow + 32 * ks + quad * 8);
        #pragma unroll
        for (int nt = 0; nt < 8; ++nt) {
            short8 bs = *(const short8*)(sm2 + (16 * nt + l15) * 104 + 32 * ks + quad * 8);
            o[nt] = __builtin_amdgcn_mfma_f32_16x16x32_bf16(as, bs, o[nt], 0, 0, 0);
        }
    }
    #pragma unroll
    for (int nt = 0; nt < 8; ++nt) {
        const int col = e0 + 16 * nt + l15;
        const float bvv = bu[col];
        #pragma unroll
        for (int r = 0; r < 4; ++r)
            out[(row0 + srow_base + r) * (size_t)EMB_D + col] = o[nt][r] + bvv;
    }
}

extern "C" void kernel_launch(void* const* d_in, const int* in_sizes, int n_in,
                              void* d_out, int out_size, void* d_ws, size_t ws_size,
                              hipStream_t stream)
{
    const float* x  = (const float*)d_in[0];
    const float* Wk = (const float*)d_in[1];
    const float* bk = (const float*)d_in[2];
    const float* Wq = (const float*)d_in[3];
    const float* bq = (const float*)d_in[4];
    const float* Wv = (const float*)d_in[5];
    const float* bv = (const float*)d_in[6];
    const float* Wu = (const float*)d_in[7];
    const float* bu = (const float*)d_in[8];
    float* out = (float*)d_out;

    char* w = (char*)d_ws;
    u16*   KQV     = (u16*)  (w + ((size_t)0  << 20));
    u16*   xb      = (u16*)  (w + ((size_t)32 << 20));
    u16*   wcat    = (u16*)  (w + ((size_t)40 << 20));
    float* biascat = (float*)(w + ((size_t)44 << 20));

    dim3 blk(256);
    hipLaunchKernelGGL(cast_k, dim3(4096, 3), blk, 0, stream, x, Wk, Wq, xb, wcat);
    hipLaunchKernelGGL(wc_k, dim3(8, 8, 2), blk, 0, stream, Wu, Wv, wcat);
    hipLaunchKernelGGL(bias_k, dim3(8), blk, 0, stream, bk, bq, bv, Wu, biascat);
    hipLaunchKernelGGL(kqv_gemm_k, dim3(64, 16), blk, 0, stream, xb, wcat, biascat, KQV);
    hipLaunchKernelGGL(heads_k, dim3(NBLK, BB, 4), blk, 0, stream, KQV, bu, out);
}

// Round 5
// 169.333 us; speedup vs baseline: 1.1670x; 1.1670x over previous
//
#include <hip/hip_runtime.h>

// BlocksparseFixedSelfAttention: B=4, T=2048, EMB=512, KBLK=64.
// R5: R4 fusion kept (Wc=Wu*Wv folds out-GEMM into heads); fixes:
//  - single fused prep kernel (cast + Wc + biascat)
//  - heads Phase A staged through LDS with global_load_lds (m97 pattern)
// ws (MB): KQV bf16 32 @0 | xb 8 @32 | wcat bf16 2048x512 @40 | biascat @44

typedef unsigned short u16;
typedef __attribute__((ext_vector_type(8))) short short8;
typedef __attribute__((ext_vector_type(4))) float f32x4;

constexpr int TDIM  = 2048;
constexpr int EMB_D = 512;
constexpr int BB    = 4;
constexpr int NBLK  = 32;    // T / 64
constexpr int LDK   = 2048;  // KQV row stride (u16)

__device__ __forceinline__ u16 f2b(float f) {
    unsigned u = __float_as_uint(f);
    unsigned r = (u + 0x7FFFu + ((u >> 16) & 1u)) >> 16;
    return (u16)r;
}

// ---------------------------------------------------------------------------
// prep: blocks [0,4096) cast x | [4096,4608) cast Wk,Wq | [4608,4864) Wc |
//       [4864,4872) biascat. One launch, no internal deps.
// ---------------------------------------------------------------------------
__global__ __launch_bounds__(256) void prep_k(
    const float* __restrict__ x, const float* __restrict__ Wk, const float* __restrict__ Wq,
    const float* __restrict__ Wv, const float* __restrict__ Wu,
    const float* __restrict__ bk, const float* __restrict__ bq, const float* __restrict__ bv,
    u16* __restrict__ xb, u16* __restrict__ wcat, float* __restrict__ biascat)
{
    const int bid = blockIdx.x, tid = threadIdx.x;
    if (bid < 4608) {
        const float* src; u16* dst; int base;
        if (bid < 4096)      { src = x;  dst = xb;            base = bid * 1024; }
        else if (bid < 4352) { src = Wk; dst = wcat;          base = (bid - 4096) * 1024; }
        else                 { src = Wq; dst = wcat + 262144; base = (bid - 4352) * 1024; }
        const int idx = base + tid * 4;
        float4 v = *(const float4*)(src + idx);
        ushort4 o = { f2b(v.x), f2b(v.y), f2b(v.z), f2b(v.w) };
        *(ushort4*)(dst + idx) = o;
    } else if (bid < 4864) {
        // Wc_half[n][k] = sum_j Wu[n][half*512+j] * Wv[j][k], 32x64 tile
        const int local = bid - 4608;
        const int half = local >> 7, rem = local & 127;
        const int n0 = (rem >> 3) * 32, k0 = (rem & 7) * 64;
        __shared__ float Wus[32][33];
        __shared__ float Wvs[32][68];
        const int n = tid >> 3, kc = (tid & 7) * 8;
        float acc[8] = {};
        for (int j0 = 0; j0 < 512; j0 += 32) {
            __syncthreads();
            {
                const int r = tid >> 3, c4 = (tid & 7) * 4;
                float4 a = *(const float4*)(Wu + (size_t)(n0 + r) * 1024 + half * 512 + j0 + c4);
                Wus[r][c4+0]=a.x; Wus[r][c4+1]=a.y; Wus[r][c4+2]=a.z; Wus[r][c4+3]=a.w;
            }
            {
                const int r = tid >> 3, c8 = (tid & 7) * 8;
                float4 a  = *(const float4*)(Wv + (size_t)(j0 + r) * 512 + k0 + c8);
                float4 a2 = *(const float4*)(Wv + (size_t)(j0 + r) * 512 + k0 + c8 + 4);
                *(float4*)(&Wvs[r][c8])     = a;
                *(float4*)(&Wvs[r][c8 + 4]) = a2;
            }
            __syncthreads();
            #pragma unroll
            for (int j = 0; j < 32; ++j) {
                const float a = Wus[n][j];
                float4 v0 = *(const float4*)(&Wvs[j][kc]);
                float4 v1 = *(const float4*)(&Wvs[j][kc + 4]);
                acc[0]+=a*v0.x; acc[1]+=a*v0.y; acc[2]+=a*v0.z; acc[3]+=a*v0.w;
                acc[4]+=a*v1.x; acc[5]+=a*v1.y; acc[6]+=a*v1.z; acc[7]+=a*v1.w;
            }
        }
        #pragma unroll
        for (int l = 0; l < 8; ++l)
            wcat[(size_t)(1024 + half * 512 + n0 + n) * 512 + k0 + kc + l] = f2b(acc[l]);
    } else {
        const int g = (bid - 4864) * 256 + tid;
        if (g < 512) biascat[g] = bk[g];
        else if (g < 1024) biascat[g] = bq[g - 512];
        else {
            const int n = (g - 1024) & 511, half = (g - 1024) >> 9;
            float s = 0.f;
            const float* wr = Wu + (size_t)n * 1024 + half * 512;
            for (int j = 0; j < 512; j += 4) {
                float4 a = *(const float4*)(wr + j);
                float4 b = *(const float4*)(bv + j);
                s += a.x*b.x + a.y*b.y + a.z*b.z + a.w*b.w;
            }
            biascat[g] = s;
        }
    }
}

// ---------------------------------------------------------------------------
// KQV GEMM: C[m][n] = sum_k xb[m][k]*wcat[n][k] + biascat[n], bf16 out ld 2048.
// 128x128 tile, BK=32, 256 threads (m97 structure).
// ---------------------------------------------------------------------------
__global__ __launch_bounds__(256) void kqv_gemm_k(
    const u16* __restrict__ A, const u16* __restrict__ W,
    const float* __restrict__ bias, u16* __restrict__ C)
{
    __shared__ u16 As[128 * 32];
    __shared__ u16 Bs[128 * 32];
    const int bm = blockIdx.x * 128;
    const int bn = blockIdx.y * 128;
    const int tid  = threadIdx.x;
    const int wid  = tid >> 6;
    const int lane = tid & 63;
    const int l15  = lane & 15;
    const int quad = lane >> 4;
    const int wm = (wid & 1) * 64;
    const int wn = (wid >> 1) * 64;

    f32x4 acc[4][4] = {};

    const int srow  = tid >> 2;
    const int skoff = (tid & 3) * 8;
    const u16* Ag = A + (size_t)(bm + srow) * EMB_D + skoff;
    const u16* Wg = W + (size_t)(bn + srow) * EMB_D + skoff;
    char* AsBase = (char*)As + wid * 1024;
    char* BsBase = (char*)Bs + wid * 1024;

    for (int k0 = 0; k0 < EMB_D; k0 += 32) {
        __syncthreads();
        __builtin_amdgcn_global_load_lds(
            (const __attribute__((address_space(1))) void*)(Ag + k0),
            (__attribute__((address_space(3))) void*)AsBase, 16, 0, 0);
        __builtin_amdgcn_global_load_lds(
            (const __attribute__((address_space(1))) void*)(Ag + (size_t)64 * EMB_D + k0),
            (__attribute__((address_space(3))) void*)(AsBase + 4096), 16, 0, 0);
        __builtin_amdgcn_global_load_lds(
            (const __attribute__((address_space(1))) void*)(Wg + k0),
            (__attribute__((address_space(3))) void*)BsBase, 16, 0, 0);
        __builtin_amdgcn_global_load_lds(
            (const __attribute__((address_space(1))) void*)(Wg + (size_t)64 * EMB_D + k0),
            (__attribute__((address_space(3))) void*)(BsBase + 4096), 16, 0, 0);
        __syncthreads();

        short8 a[4], b[4];
        #pragma unroll
        for (int i = 0; i < 4; ++i)
            a[i] = *(const short8*)((const short*)As + (wm + 16 * i + l15) * 32 + quad * 8);
        #pragma unroll
        for (int j = 0; j < 4; ++j)
            b[j] = *(const short8*)((const short*)Bs + (wn + 16 * j + l15) * 32 + quad * 8);
        #pragma unroll
        for (int i = 0; i < 4; ++i)
            #pragma unroll
            for (int j = 0; j < 4; ++j)
                acc[i][j] = __builtin_amdgcn_mfma_f32_16x16x32_bf16(a[i], b[j], acc[i][j], 0, 0, 0);
    }

    #pragma unroll
    for (int i = 0; i < 4; ++i) {
        #pragma unroll
        for (int j = 0; j < 4; ++j) {
            const int col = bn + wn + 16 * j + l15;
            const float bvv = bias[col];
            #pragma unroll
            for (int r = 0; r < 4; ++r) {
                const int row = bm + wm + 16 * i + quad * 4 + r;
                C[(size_t)row * LDK + col] = f2b(acc[i][j][r] + bvv);
            }
        }
    }
}

// ---------------------------------------------------------------------------
// heads: grid (32 blk, 4 b, 4 e-chunk).
//  Phase A (LDS-staged, BK=64): S1 = K_blk.Q_blk^T (64x64), S2 = K_blk.Qsel^T
//  (64x32), K=512; masks c<=r / m<=blk; S -> smA bf16.
//  Phase B: out[:, e0:+128] = [S1|S2] @ [VU1_blk ; VU2sel]^T + bu (K=96).
//  VU^T staged at kernel top (latency overlaps Phase A).
// ---------------------------------------------------------------------------
__global__ __launch_bounds__(256) void heads_k(
    const u16* __restrict__ KQV, const float* __restrict__ bu, float* __restrict__ out)
{
    __shared__ u16 smA[64 * 104];     // [row][0:64 S1 | 64:96 S2]
    __shared__ u16 smVT[128 * 104];   // [e][0:64 VU1^T | 64:96 VU2sel^T]
    __shared__ u16 pK[2][64 * 32];    // k-panels (BK=64 = 2 x 32)
    __shared__ u16 pQ[2][64 * 32];
    __shared__ u16 pQs[2][32 * 32];

    const int blk = blockIdx.x, b = blockIdx.y;
    const int e0 = blockIdx.z * 128;
    const int tid = threadIdx.x;
    const int wid = tid >> 6, lane = tid & 63;
    const int l15 = lane & 15, quad = lane >> 4;
    const size_t row0 = (size_t)b * TDIM + (size_t)blk * 64;
    const size_t brow = (size_t)b * TDIM;
    const int srow_base = 16 * wid + quad * 4;

    // ---- VU^T staging (independent of S; overlaps Phase A latency) ----
    #pragma unroll
    for (int it = 0; it < 4; ++it) {
        const int id = tid + 256 * it;
        const int c  = id & 63;
        const int eo = (id >> 6) * 8;
        short8 v = *(const short8*)(KQV + (row0 + c) * (size_t)LDK + 1024 + e0 + eo);
        #pragma unroll
        for (int i = 0; i < 8; ++i) smVT[(eo + i) * 104 + c] = (u16)v[i];
    }
    #pragma unroll
    for (int it = 0; it < 2; ++it) {
        const int id = tid + 256 * it;
        const int m  = id & 31;
        const int eo = (id >> 5) * 8;
        short8 v = *(const short8*)(KQV + (brow + 64 * m) * (size_t)LDK + 1536 + e0 + eo);
        #pragma unroll
        for (int i = 0; i < 8; ++i) smVT[(eo + i) * 104 + 64 + m] = (u16)v[i];
    }

    // ---- Phase A ----
    f32x4 s1[4] = {}; f32x4 s2[2] = {};
    const int srow  = tid >> 2;          // 0..63
    const int skoff = (tid & 3) * 8;
    const int qsrow = srow & 31;
    const int qsp   = tid >> 7;          // Qsel panel index for this wave pair
    const u16* Kg  = KQV + (row0 + srow) * (size_t)LDK + skoff;
    const u16* Qg  = KQV + (row0 + srow) * (size_t)LDK + 512 + skoff;
    const u16* Qsg = KQV + (brow + (size_t)64 * qsrow) * (size_t)LDK + 512 + qsp * 32 + skoff;
    char* dK  = (char*)pK  + wid * 1024;
    char* dQ  = (char*)pQ  + wid * 1024;
    char* dQs = (char*)pQs + wid * 1024;

    for (int k0 = 0; k0 < 512; k0 += 64) {
        __syncthreads();
        __builtin_amdgcn_global_load_lds(
            (const __attribute__((address_space(1))) void*)(Kg + k0),
            (__attribute__((address_space(3))) void*)dK, 16, 0, 0);
        __builtin_amdgcn_global_load_lds(
            (const __attribute__((address_space(1))) void*)(Kg + k0 + 32),
            (__attribute__((address_space(3))) void*)(dK + 4096), 16, 0, 0);
        __builtin_amdgcn_global_load_lds(
            (const __attribute__((address_space(1))) void*)(Qg + k0),
            (__attribute__((address_space(3))) void*)dQ, 16, 0, 0);
        __builtin_amdgcn_global_load_lds(
            (const __attribute__((address_space(1))) void*)(Qg + k0 + 32),
            (__attribute__((address_space(3))) void*)(dQ + 4096), 16, 0, 0);
        __builtin_amdgcn_global_load_lds(
            (const __attribute__((address_space(1))) void*)(Qsg + k0),
            (__attribute__((address_space(3))) void*)dQs, 16, 0, 0);
        __syncthreads();

        short8 a0 = *(const short8*)(pK[0] + (16 * wid + l15) * 32 + quad * 8);
        short8 a1 = *(const short8*)(pK[1] + (16 * wid + l15) * 32 + quad * 8);
        #pragma unroll
        for (int j = 0; j < 4; ++j) {
            short8 b0 = *(const short8*)(pQ[0] + (16 * j + l15) * 32 + quad * 8);
            short8 b1 = *(const short8*)(pQ[1] + (16 * j + l15) * 32 + quad * 8);
            s1[j] = __builtin_amdgcn_mfma_f32_16x16x32_bf16(a0, b0, s1[j], 0, 0, 0);
            s1[j] = __builtin_amdgcn_mfma_f32_16x16x32_bf16(a1, b1, s1[j], 0, 0, 0);
        }
        #pragma unroll
        for (int j = 0; j < 2; ++j) {
            short8 b0 = *(const short8*)(pQs[0] + (16 * j + l15) * 32 + quad * 8);
            short8 b1 = *(const short8*)(pQs[1] + (16 * j + l15) * 32 + quad * 8);
            s2[j] = __builtin_amdgcn_mfma_f32_16x16x32_bf16(a0, b0, s2[j], 0, 0, 0);
            s2[j] = __builtin_amdgcn_mfma_f32_16x16x32_bf16(a1, b1, s2[j], 0, 0, 0);
        }
    }

    // mask + store S to LDS bf16
    #pragma unroll
    for (int j = 0; j < 4; ++j)
        #pragma unroll
        for (int r = 0; r < 4; ++r) {
            const int rr = srow_base + r;
            const int cc = 16 * j + l15;
            smA[rr * 104 + cc] = f2b((cc <= rr) ? s1[j][r] : 0.0f);
        }
    #pragma unroll
    for (int j = 0; j < 2; ++j)
        #pragma unroll
        for (int r = 0; r < 4; ++r) {
            const int m  = 16 * j + l15;
            const int rr = srow_base + r;
            smA[rr * 104 + 64 + m] = f2b((m <= blk) ? s2[j][r] : 0.0f);
        }
    __syncthreads();

    // ---- Phase B: out = [S1|S2] @ smVT^T  (K=96, N=128) ----
    f32x4 o[8] = {};
    const u16* arow = smA + (16 * wid + l15) * 104;
    #pragma unroll
    for (int ks = 0; ks < 3; ++ks) {
        short8 as = *(const short8*)(arow + 32 * ks + quad * 8);
        #pragma unroll
        for (int nt = 0; nt < 8; ++nt) {
            short8 bs = *(const short8*)(smVT + (16 * nt + l15) * 104 + 32 * ks + quad * 8);
            o[nt] = __builtin_amdgcn_mfma_f32_16x16x32_bf16(as, bs, o[nt], 0, 0, 0);
        }
    }
    #pragma unroll
    for (int nt = 0; nt < 8; ++nt) {
        const int col = e0 + 16 * nt + l15;
        const float bvv = bu[col];
        #pragma unroll
        for (int r = 0; r < 4; ++r)
            out[(row0 + srow_base + r) * (size_t)EMB_D + col] = o[nt][r] + bvv;
    }
}

extern "C" void kernel_launch(void* const* d_in, const int* in_sizes, int n_in,
                              void* d_out, int out_size, void* d_ws, size_t ws_size,
                              hipStream_t stream)
{
    const float* x  = (const float*)d_in[0];
    const float* Wk = (const float*)d_in[1];
    const float* bk = (const float*)d_in[2];
    const float* Wq = (const float*)d_in[3];
    const float* bq = (const float*)d_in[4];
    const float* Wv = (const float*)d_in[5];
    const float* bv = (const float*)d_in[6];
    const float* Wu = (const float*)d_in[7];
    const float* bu = (const float*)d_in[8];
    float* out = (float*)d_out;

    char* w = (char*)d_ws;
    u16*   KQV     = (u16*)  (w + ((size_t)0  << 20));
    u16*   xb      = (u16*)  (w + ((size_t)32 << 20));
    u16*   wcat    = (u16*)  (w + ((size_t)40 << 20));
    float* biascat = (float*)(w + ((size_t)44 << 20));

    dim3 blk(256);
    hipLaunchKernelGGL(prep_k, dim3(4872), blk, 0, stream,
                       x, Wk, Wq, Wv, Wu, bk, bq, bv, xb, wcat, biascat);
    hipLaunchKernelGGL(kqv_gemm_k, dim3(64, 16), blk, 0, stream, xb, wcat, biascat, KQV);
    hipLaunchKernelGGL(heads_k, dim3(NBLK, BB, 4), blk, 0, stream, KQV, bu, out);
}

// Round 6
// 147.650 us; speedup vs baseline: 1.3384x; 1.1469x over previous
//
#include <hip/hip_runtime.h>

// BlocksparseFixedSelfAttention: B=4, T=2048, EMB=512, KBLK=64.
// R6: fusion kept (Wc=Wu*Wv folds out-GEMM into heads). prep rebuilt as pure
// bandwidth (casts + Wv transpose-cast + bias reduce); Wc moved to bf16 MFMA.
// ws (MB): KQV bf16 32 @0 | xb 8 @32 | wcat bf16 2048x512 @40 | wvtb @42 |
//          wub @43 | biascat @44

typedef unsigned short u16;
typedef __attribute__((ext_vector_type(8))) short short8;
typedef __attribute__((ext_vector_type(4))) float f32x4;

constexpr int TDIM  = 2048;
constexpr int EMB_D = 512;
constexpr int BB    = 4;
constexpr int NBLK  = 32;    // T / 64
constexpr int LDK   = 2048;  // KQV row stride (u16)

__device__ __forceinline__ u16 f2b(float f) {
    unsigned u = __float_as_uint(f);
    unsigned r = (u + 0x7FFFu + ((u >> 16) & 1u)) >> 16;
    return (u16)r;
}

// ---------------------------------------------------------------------------
// prep (one launch, all parts independent, memory-bound):
//  [0,4096)    cast x -> xb
//  [4096,4352) cast Wk -> wcat[0:512]
//  [4352,4608) cast Wq -> wcat[512:1024]
//  [4608,5120) cast Wu -> wub
//  [5120,5184) transpose-cast Wv -> wvtb[k][j]
//  [5184,5200) biascat[1024+o] = Wu[o&511][.] . bv  (4 lanes/output + shfl)
//  5200        biascat[0:1024] = [bk|bq]
// ---------------------------------------------------------------------------
__global__ __launch_bounds__(256) void prep_k(
    const float* __restrict__ x, const float* __restrict__ Wk, const float* __restrict__ Wq,
    const float* __restrict__ Wv, const float* __restrict__ Wu,
    const float* __restrict__ bk, const float* __restrict__ bq, const float* __restrict__ bv,
    u16* __restrict__ xb, u16* __restrict__ wcat, u16* __restrict__ wvtb,
    u16* __restrict__ wub, float* __restrict__ biascat)
{
    const int bid = blockIdx.x, tid = threadIdx.x;
    if (bid < 5120) {
        const float* src; u16* dst; int base;
        if (bid < 4096)      { src = x;  dst = xb;            base = bid * 1024; }
        else if (bid < 4352) { src = Wk; dst = wcat;          base = (bid - 4096) * 1024; }
        else if (bid < 4608) { src = Wq; dst = wcat + 262144; base = (bid - 4352) * 1024; }
        else                 { src = Wu; dst = wub;           base = (bid - 4608) * 1024; }
        const int idx = base + tid * 4;
        float4 v = *(const float4*)(src + idx);
        ushort4 o = { f2b(v.x), f2b(v.y), f2b(v.z), f2b(v.w) };
        *(ushort4*)(dst + idx) = o;
    } else if (bid < 5184) {
        // 64x64 transpose tile of Wv
        __shared__ float T[64][65];
        const int t = bid - 5120;
        const int j0 = (t >> 3) * 64, k0 = (t & 7) * 64;
        const int rr = tid >> 4, c4 = (tid & 15) * 4;
        #pragma unroll
        for (int it = 0; it < 4; ++it) {
            const int j = rr + it * 16;
            float4 v = *(const float4*)(Wv + (size_t)(j0 + j) * 512 + k0 + c4);
            T[c4+0][j] = v.x; T[c4+1][j] = v.y; T[c4+2][j] = v.z; T[c4+3][j] = v.w;
        }
        __syncthreads();
        #pragma unroll
        for (int it = 0; it < 4; ++it) {
            const int k = rr + it * 16;
            ushort4 o = { f2b(T[k][c4+0]), f2b(T[k][c4+1]), f2b(T[k][c4+2]), f2b(T[k][c4+3]) };
            *(ushort4*)(wvtb + (size_t)(k0 + k) * 512 + j0 + c4) = o;
        }
    } else if (bid < 5200) {
        // Wu.bv dot: output o = (bid-5184)*64 + tid/4, lane-part p = tid%4
        const int o = (bid - 5184) * 64 + (tid >> 2);
        const int p = tid & 3;
        const int n = o & 511, half = o >> 9;
        const float* wr = Wu + (size_t)n * 1024 + half * 512 + p * 128;
        const float* br = bv + p * 128;
        float s = 0.f;
        #pragma unroll
        for (int j = 0; j < 128; j += 4) {
            float4 a = *(const float4*)(wr + j);
            float4 b = *(const float4*)(br + j);
            s += a.x*b.x + a.y*b.y + a.z*b.z + a.w*b.w;
        }
        s += __shfl_xor(s, 1);
        s += __shfl_xor(s, 2);
        if (p == 0) biascat[1024 + o] = s;
    } else {
        const int idx = tid * 4;
        float4 v = (idx < 512) ? *(const float4*)(bk + idx)
                               : *(const float4*)(bq + idx - 512);
        *(float4*)(biascat + idx) = v;
    }
}

// ---------------------------------------------------------------------------
// wc_gemm: Wc[m][k] = sum_j wub[m&511][ (m>>9)*512 + j ] * wvtb[k][j]
// -> wcat rows 1024+m. bf16 MFMA, 128x128 tile, BK=32 (m97 structure).
// grid (8,4). M=1024, N=512, K=512.
// ---------------------------------------------------------------------------
__global__ __launch_bounds__(256) void wc_gemm_k(
    const u16* __restrict__ wub, const u16* __restrict__ wvtb, u16* __restrict__ wcat)
{
    __shared__ u16 As[128 * 32];
    __shared__ u16 Bs[128 * 32];
    const int bm = blockIdx.x * 128;
    const int bn = blockIdx.y * 128;
    const int tid  = threadIdx.x;
    const int wid  = tid >> 6;
    const int lane = tid & 63;
    const int l15  = lane & 15;
    const int quad = lane >> 4;
    const int wm = (wid & 1) * 64;
    const int wn = (wid >> 1) * 64;

    f32x4 acc[4][4] = {};

    const int srow  = tid >> 2;
    const int skoff = (tid & 3) * 8;
    const int m0 = bm + srow, m1 = bm + 64 + srow;
    const u16* Ag0 = wub + (size_t)(m0 & 511) * 1024 + (m0 >> 9) * 512 + skoff;
    const u16* Ag1 = wub + (size_t)(m1 & 511) * 1024 + (m1 >> 9) * 512 + skoff;
    const u16* Bg  = wvtb + (size_t)(bn + srow) * 512 + skoff;
    char* AsBase = (char*)As + wid * 1024;
    char* BsBase = (char*)Bs + wid * 1024;

    for (int k0 = 0; k0 < 512; k0 += 32) {
        __syncthreads();
        __builtin_amdgcn_global_load_lds(
            (const __attribute__((address_space(1))) void*)(Ag0 + k0),
            (__attribute__((address_space(3))) void*)AsBase, 16, 0, 0);
        __builtin_amdgcn_global_load_lds(
            (const __attribute__((address_space(1))) void*)(Ag1 + k0),
            (__attribute__((address_space(3))) void*)(AsBase + 4096), 16, 0, 0);
        __builtin_amdgcn_global_load_lds(
            (const __attribute__((address_space(1))) void*)(Bg + k0),
            (__attribute__((address_space(3))) void*)BsBase, 16, 0, 0);
        __builtin_amdgcn_global_load_lds(
            (const __attribute__((address_space(1))) void*)(Bg + (size_t)64 * 512 + k0),
            (__attribute__((address_space(3))) void*)(BsBase + 4096), 16, 0, 0);
        __syncthreads();

        short8 a[4], b[4];
        #pragma unroll
        for (int i = 0; i < 4; ++i)
            a[i] = *(const short8*)((const short*)As + (wm + 16 * i + l15) * 32 + quad * 8);
        #pragma unroll
        for (int j = 0; j < 4; ++j)
            b[j] = *(const short8*)((const short*)Bs + (wn + 16 * j + l15) * 32 + quad * 8);
        #pragma unroll
        for (int i = 0; i < 4; ++i)
            #pragma unroll
            for (int j = 0; j < 4; ++j)
                acc[i][j] = __builtin_amdgcn_mfma_f32_16x16x32_bf16(a[i], b[j], acc[i][j], 0, 0, 0);
    }

    #pragma unroll
    for (int i = 0; i < 4; ++i)
        #pragma unroll
        for (int j = 0; j < 4; ++j) {
            const int col = bn + wn + 16 * j + l15;
            #pragma unroll
            for (int r = 0; r < 4; ++r) {
                const int row = bm + wm + 16 * i + quad * 4 + r;
                wcat[(size_t)(1024 + row) * 512 + col] = f2b(acc[i][j][r]);
            }
        }
}

// ---------------------------------------------------------------------------
// KQV GEMM: C[m][n] = sum_k xb[m][k]*wcat[n][k] + biascat[n], bf16 out ld 2048.
// 128x128 tile, BK=32, 256 threads (m97 structure).
// ---------------------------------------------------------------------------
__global__ __launch_bounds__(256) void kqv_gemm_k(
    const u16* __restrict__ A, const u16* __restrict__ W,
    const float* __restrict__ bias, u16* __restrict__ C)
{
    __shared__ u16 As[128 * 32];
    __shared__ u16 Bs[128 * 32];
    const int bm = blockIdx.x * 128;
    const int bn = blockIdx.y * 128;
    const int tid  = threadIdx.x;
    const int wid  = tid >> 6;
    const int lane = tid & 63;
    const int l15  = lane & 15;
    const int quad = lane >> 4;
    const int wm = (wid & 1) * 64;
    const int wn = (wid >> 1) * 64;

    f32x4 acc[4][4] = {};

    const int srow  = tid >> 2;
    const int skoff = (tid & 3) * 8;
    const u16* Ag = A + (size_t)(bm + srow) * EMB_D + skoff;
    const u16* Wg = W + (size_t)(bn + srow) * EMB_D + skoff;
    char* AsBase = (char*)As + wid * 1024;
    char* BsBase = (char*)Bs + wid * 1024;

    for (int k0 = 0; k0 < EMB_D; k0 += 32) {
        __syncthreads();
        __builtin_amdgcn_global_load_lds(
            (const __attribute__((address_space(1))) void*)(Ag + k0),
            (__attribute__((address_space(3))) void*)AsBase, 16, 0, 0);
        __builtin_amdgcn_global_load_lds(
            (const __attribute__((address_space(1))) void*)(Ag + (size_t)64 * EMB_D + k0),
            (__attribute__((address_space(3))) void*)(AsBase + 4096), 16, 0, 0);
        __builtin_amdgcn_global_load_lds(
            (const __attribute__((address_space(1))) void*)(Wg + k0),
            (__attribute__((address_space(3))) void*)BsBase, 16, 0, 0);
        __builtin_amdgcn_global_load_lds(
            (const __attribute__((address_space(1))) void*)(Wg + (size_t)64 * EMB_D + k0),
            (__attribute__((address_space(3))) void*)(BsBase + 4096), 16, 0, 0);
        __syncthreads();

        short8 a[4], b[4];
        #pragma unroll
        for (int i = 0; i < 4; ++i)
            a[i] = *(const short8*)((const short*)As + (wm + 16 * i + l15) * 32 + quad * 8);
        #pragma unroll
        for (int j = 0; j < 4; ++j)
            b[j] = *(const short8*)((const short*)Bs + (wn + 16 * j + l15) * 32 + quad * 8);
        #pragma unroll
        for (int i = 0; i < 4; ++i)
            #pragma unroll
            for (int j = 0; j < 4; ++j)
                acc[i][j] = __builtin_amdgcn_mfma_f32_16x16x32_bf16(a[i], b[j], acc[i][j], 0, 0, 0);
    }

    #pragma unroll
    for (int i = 0; i < 4; ++i) {
        #pragma unroll
        for (int j = 0; j < 4; ++j) {
            const int col = bn + wn + 16 * j + l15;
            const float bvv = bias[col];
            #pragma unroll
            for (int r = 0; r < 4; ++r) {
                const int row = bm + wm + 16 * i + quad * 4 + r;
                C[(size_t)row * LDK + col] = f2b(acc[i][j][r] + bvv);
            }
        }
    }
}

// ---------------------------------------------------------------------------
// heads: grid (32 blk, 4 b, 4 e-chunk).
//  Phase A (LDS-staged, BK=64): S1 = K_blk.Q_blk^T (64x64), S2 = K_blk.Qsel^T
//  (64x32), K=512; masks c<=r / m<=blk; S -> smA bf16.
//  Phase B: out[:, e0:+128] = [S1|S2] @ [VU1_blk ; VU2sel]^T + bu (K=96).
// ---------------------------------------------------------------------------
__global__ __launch_bounds__(256) void heads_k(
    const u16* __restrict__ KQV, const float* __restrict__ bu, float* __restrict__ out)
{
    __shared__ u16 smA[64 * 104];     // [row][0:64 S1 | 64:96 S2]
    __shared__ u16 smVT[128 * 104];   // [e][0:64 VU1^T | 64:96 VU2sel^T]
    __shared__ u16 pK[2][64 * 32];    // k-panels (BK=64 = 2 x 32)
    __shared__ u16 pQ[2][64 * 32];
    __shared__ u16 pQs[2][32 * 32];

    const int blk = blockIdx.x, b = blockIdx.y;
    const int e0 = blockIdx.z * 128;
    const int tid = threadIdx.x;
    const int wid = tid >> 6, lane = tid & 63;
    const int l15 = lane & 15, quad = lane >> 4;
    const size_t row0 = (size_t)b * TDIM + (size_t)blk * 64;
    const size_t brow = (size_t)b * TDIM;
    const int srow_base = 16 * wid + quad * 4;

    // ---- VU^T staging (independent of S; overlaps Phase A latency) ----
    #pragma unroll
    for (int it = 0; it < 4; ++it) {
        const int id = tid + 256 * it;
        const int c  = id & 63;
        const int eo = (id >> 6) * 8;
        short8 v = *(const short8*)(KQV + (row0 + c) * (size_t)LDK + 1024 + e0 + eo);
        #pragma unroll
        for (int i = 0; i < 8; ++i) smVT[(eo + i) * 104 + c] = (u16)v[i];
    }
    #pragma unroll
    for (int it = 0; it < 2; ++it) {
        const int id = tid + 256 * it;
        const int m  = id & 31;
        const int eo = (id >> 5) * 8;
        short8 v = *(const short8*)(KQV + (brow + 64 * m) * (size_t)LDK + 1536 + e0 + eo);
        #pragma unroll
        for (int i = 0; i < 8; ++i) smVT[(eo + i) * 104 + 64 + m] = (u16)v[i];
    }

    // ---- Phase A ----
    f32x4 s1[4] = {}; f32x4 s2[2] = {};
    const int srow  = tid >> 2;
    const int skoff = (tid & 3) * 8;
    const int qsrow = srow & 31;
    const int qsp   = tid >> 7;
    const u16* Kg  = KQV + (row0 + srow) * (size_t)LDK + skoff;
    const u16* Qg  = KQV + (row0 + srow) * (size_t)LDK + 512 + skoff;
    const u16* Qsg = KQV + (brow + (size_t)64 * qsrow) * (size_t)LDK + 512 + qsp * 32 + skoff;
    char* dK  = (char*)pK  + wid * 1024;
    char* dQ  = (char*)pQ  + wid * 1024;
    char* dQs = (char*)pQs + wid * 1024;

    for (int k0 = 0; k0 < 512; k0 += 64) {
        __syncthreads();
        __builtin_amdgcn_global_load_lds(
            (const __attribute__((address_space(1))) void*)(Kg + k0),
            (__attribute__((address_space(3))) void*)dK, 16, 0, 0);
        __builtin_amdgcn_global_load_lds(
            (const __attribute__((address_space(1))) void*)(Kg + k0 + 32),
            (__attribute__((address_space(3))) void*)(dK + 4096), 16, 0, 0);
        __builtin_amdgcn_global_load_lds(
            (const __attribute__((address_space(1))) void*)(Qg + k0),
            (__attribute__((address_space(3))) void*)dQ, 16, 0, 0);
        __builtin_amdgcn_global_load_lds(
            (const __attribute__((address_space(1))) void*)(Qg + k0 + 32),
            (__attribute__((address_space(3))) void*)(dQ + 4096), 16, 0, 0);
        __builtin_amdgcn_global_load_lds(
            (const __attribute__((address_space(1))) void*)(Qsg + k0),
            (__attribute__((address_space(3))) void*)dQs, 16, 0, 0);
        __syncthreads();

        short8 a0 = *(const short8*)(pK[0] + (16 * wid + l15) * 32 + quad * 8);
        short8 a1 = *(const short8*)(pK[1] + (16 * wid + l15) * 32 + quad * 8);
        #pragma unroll
        for (int j = 0; j < 4; ++j) {
            short8 b0 = *(const short8*)(pQ[0] + (16 * j + l15) * 32 + quad * 8);
            short8 b1 = *(const short8*)(pQ[1] + (16 * j + l15) * 32 + quad * 8);
            s1[j] = __builtin_amdgcn_mfma_f32_16x16x32_bf16(a0, b0, s1[j], 0, 0, 0);
            s1[j] = __builtin_amdgcn_mfma_f32_16x16x32_bf16(a1, b1, s1[j], 0, 0, 0);
        }
        #pragma unroll
        for (int j = 0; j < 2; ++j) {
            short8 b0 = *(const short8*)(pQs[0] + (16 * j + l15) * 32 + quad * 8);
            short8 b1 = *(const short8*)(pQs[1] + (16 * j + l15) * 32 + quad * 8);
            s2[j] = __builtin_amdgcn_mfma_f32_16x16x32_bf16(a0, b0, s2[j], 0, 0, 0);
            s2[j] = __builtin_amdgcn_mfma_f32_16x16x32_bf16(a1, b1, s2[j], 0, 0, 0);
        }
    }

    #pragma unroll
    for (int j = 0; j < 4; ++j)
        #pragma unroll
        for (int r = 0; r < 4; ++r) {
            const int rr = srow_base + r;
            const int cc = 16 * j + l15;
            smA[rr * 104 + cc] = f2b((cc <= rr) ? s1[j][r] : 0.0f);
        }
    #pragma unroll
    for (int j = 0; j < 2; ++j)
        #pragma unroll
        for (int r = 0; r < 4; ++r) {
            const int m  = 16 * j + l15;
            const int rr = srow_base + r;
            smA[rr * 104 + 64 + m] = f2b((m <= blk) ? s2[j][r] : 0.0f);
        }
    __syncthreads();

    // ---- Phase B: out = [S1|S2] @ smVT^T  (K=96, N=128) ----
    f32x4 o[8] = {};
    const u16* arow = smA + (16 * wid + l15) * 104;
    #pragma unroll
    for (int ks = 0; ks < 3; ++ks) {
        short8 as = *(const short8*)(arow + 32 * ks + quad * 8);
        #pragma unroll
        for (int nt = 0; nt < 8; ++nt) {
            short8 bs = *(const short8*)(smVT + (16 * nt + l15) * 104 + 32 * ks + quad * 8);
            o[nt] = __builtin_amdgcn_mfma_f32_16x16x32_bf16(as, bs, o[nt], 0, 0, 0);
        }
    }
    #pragma unroll
    for (int nt = 0; nt < 8; ++nt) {
        const int col = e0 + 16 * nt + l15;
        const float bvv = bu[col];
        #pragma unroll
        for (int r = 0; r < 4; ++r)
            out[(row0 + srow_base + r) * (size_t)EMB_D + col] = o[nt][r] + bvv;
    }
}

extern "C" void kernel_launch(void* const* d_in, const int* in_sizes, int n_in,
                              void* d_out, int out_size, void* d_ws, size_t ws_size,
                              hipStream_t stream)
{
    const float* x  = (const float*)d_in[0];
    const float* Wk = (const float*)d_in[1];
    const float* bk = (const float*)d_in[2];
    const float* Wq = (const float*)d_in[3];
    const float* bq = (const float*)d_in[4];
    const float* Wv = (const float*)d_in[5];
    const float* bv = (const float*)d_in[6];
    const float* Wu = (const float*)d_in[7];
    const float* bu = (const float*)d_in[8];
    float* out = (float*)d_out;

    char* w = (char*)d_ws;
    u16*   KQV     = (u16*)  (w + ((size_t)0  << 20));
    u16*   xb      = (u16*)  (w + ((size_t)32 << 20));
    u16*   wcat    = (u16*)  (w + ((size_t)40 << 20));
    u16*   wvtb    = (u16*)  (w + ((size_t)42 << 20));
    u16*   wub     = (u16*)  (w + ((size_t)43 << 20));
    float* biascat = (float*)(w + ((size_t)44 << 20));

    dim3 blk(256);
    hipLaunchKernelGGL(prep_k, dim3(5201), blk, 0, stream,
                       x, Wk, Wq, Wv, Wu, bk, bq, bv, xb, wcat, wvtb, wub, biascat);
    hipLaunchKernelGGL(wc_gemm_k, dim3(8, 4), blk, 0, stream, wub, wvtb, wcat);
    hipLaunchKernelGGL(kqv_gemm_k, dim3(64, 16), blk, 0, stream, xb, wcat, biascat, KQV);
    hipLaunchKernelGGL(heads_k, dim3(NBLK, BB, 4), blk, 0, stream, KQV, bu, out);
}